// Round 1
// baseline (1707.714 us; speedup 1.0000x reference)
//
#include <hip/hip_runtime.h>
#include <hip/hip_bf16.h>
#include <math.h>

// PosNetEncoder: B=2, I=J=1024, D=1024, H=16, DH=64, K=64 (R=129), FF=4096
#define D_   1024
#define H_   16
#define DH_  64
#define FF_  4096
#define R_   129
#define I_   1024
#define B_   2
#define MROWS 2048   // B_*I_

__device__ __forceinline__ float gelu_f(float x) {
    return 0.5f * x * (1.0f + erff(x * 0.7071067811865476f));
}

// ---------------- LayerNorm over rows of length 1024 (256 thr, float4) -------
__global__ __launch_bounds__(256) void ln_kernel(const float* __restrict__ in,
        float* __restrict__ out, const float* __restrict__ gw,
        const float* __restrict__ bw) {
    __shared__ float shs[4], shq[4];
    int row = blockIdx.x;
    int t = threadIdx.x;
    float4 v = reinterpret_cast<const float4*>(in + (size_t)row * D_)[t];
    float s = v.x + v.y + v.z + v.w;
#pragma unroll
    for (int off = 32; off > 0; off >>= 1) s += __shfl_down(s, off, 64);
    if ((t & 63) == 0) shs[t >> 6] = s;
    __syncthreads();
    float mean = (shs[0] + shs[1] + shs[2] + shs[3]) * (1.0f / D_);
    float d0 = v.x - mean, d1 = v.y - mean, d2 = v.z - mean, d3 = v.w - mean;
    float q = d0 * d0 + d1 * d1 + d2 * d2 + d3 * d3;
#pragma unroll
    for (int off = 32; off > 0; off >>= 1) q += __shfl_down(q, off, 64);
    if ((t & 63) == 0) shq[t >> 6] = q;
    __syncthreads();
    float var = (shq[0] + shq[1] + shq[2] + shq[3]) * (1.0f / D_);
    float rstd = rsqrtf(var + 1e-5f);
    float4 g4 = reinterpret_cast<const float4*>(gw)[t];
    float4 b4 = reinterpret_cast<const float4*>(bw)[t];
    float4 o;
    o.x = d0 * rstd * g4.x + b4.x;
    o.y = d1 * rstd * g4.y + b4.y;
    o.z = d2 * rstd * g4.z + b4.z;
    o.w = d3 * rstd * g4.w + b4.w;
    reinterpret_cast<float4*>(out + (size_t)row * D_)[t] = o;
}

// ---------------- fp32 GEMM: C = act(A[M,K]@W[K,N] + bias) (+res) ------------
// 64x64 tile, BK=16, 256 threads, 4x4 per thread. ACT: 0 none, 1 gelu, 2 relu.
template<int ACT, int RES>
__global__ __launch_bounds__(256) void gemm_f32(const float* __restrict__ A,
        const float* __restrict__ W, const float* __restrict__ bias,
        const float* __restrict__ res, float* __restrict__ C,
        int M, int N, int Kd) {
    __shared__ float As[16][68];   // [k][m], pad 68 keeps 16B align, 2-way max
    __shared__ float Bs[16][68];   // [k][n]
    int t = threadIdx.x;
    int m0 = blockIdx.y * 64, n0 = blockIdx.x * 64;
    int tx4 = (t & 15) * 4, ty4 = (t >> 4) * 4;
    float acc[4][4] = {};
    for (int k0 = 0; k0 < Kd; k0 += 16) {
#pragma unroll
        for (int i = 0; i < 4; i++) {
            int e = t + i * 256;
            As[e & 15][e >> 4] = A[(size_t)(m0 + (e >> 4)) * Kd + k0 + (e & 15)];
        }
#pragma unroll
        for (int i = 0; i < 4; i++) {
            int e = t + i * 256;
            Bs[e >> 6][e & 63] = W[(size_t)(k0 + (e >> 6)) * N + n0 + (e & 63)];
        }
        __syncthreads();
#pragma unroll
        for (int k = 0; k < 16; k++) {
            float a0 = As[k][ty4], a1 = As[k][ty4 + 1], a2 = As[k][ty4 + 2], a3 = As[k][ty4 + 3];
            float b0 = Bs[k][tx4], b1 = Bs[k][tx4 + 1], b2 = Bs[k][tx4 + 2], b3 = Bs[k][tx4 + 3];
            acc[0][0] += a0 * b0; acc[0][1] += a0 * b1; acc[0][2] += a0 * b2; acc[0][3] += a0 * b3;
            acc[1][0] += a1 * b0; acc[1][1] += a1 * b1; acc[1][2] += a1 * b2; acc[1][3] += a1 * b3;
            acc[2][0] += a2 * b0; acc[2][1] += a2 * b1; acc[2][2] += a2 * b2; acc[2][3] += a2 * b3;
            acc[3][0] += a3 * b0; acc[3][1] += a3 * b1; acc[3][2] += a3 * b2; acc[3][3] += a3 * b3;
        }
        __syncthreads();
    }
    float4 bia = reinterpret_cast<const float4*>(bias + n0)[t & 15];
#pragma unroll
    for (int r = 0; r < 4; r++) {
        int m = m0 + ty4 + r;
        float4 o;
        o.x = acc[r][0] + bia.x; o.y = acc[r][1] + bia.y;
        o.z = acc[r][2] + bia.z; o.w = acc[r][3] + bia.w;
        if (ACT == 1) { o.x = gelu_f(o.x); o.y = gelu_f(o.y); o.z = gelu_f(o.z); o.w = gelu_f(o.w); }
        if (ACT == 2) { o.x = fmaxf(o.x, 0.f); o.y = fmaxf(o.y, 0.f); o.z = fmaxf(o.z, 0.f); o.w = fmaxf(o.w, 0.f); }
        if (RES) {
            float4 rv = reinterpret_cast<const float4*>(res + (size_t)m * N + n0)[t & 15];
            o.x += rv.x; o.y += rv.y; o.z += rv.z; o.w += rv.w;
        }
        reinterpret_cast<float4*>(C + (size_t)m * N + n0)[t & 15] = o;
    }
}

// ---------------- aa[b,h,i,j] = sum_d q1[b,i,h,d]*kh[b,j,h,d] ---------------
// grid (J/32, I/32, B*H); writes straight into d_out's `a` region (scratch).
__global__ __launch_bounds__(256) void aa_kernel(const float* __restrict__ q1,
        const float* __restrict__ kh, float* __restrict__ aa) {
    int bh = blockIdx.z, b = bh >> 4, h = bh & 15;
    int i0 = blockIdx.y * 32, j0 = blockIdx.x * 32;
    __shared__ float Qs[32][65];
    __shared__ float Ks[32][65];
    for (int e = threadIdx.x; e < 2048; e += 256) {
        int r = e >> 6, d = e & 63;
        Qs[r][d] = q1[((size_t)(b * I_ + i0 + r)) * D_ + h * DH_ + d];
        Ks[r][d] = kh[((size_t)(b * I_ + j0 + r)) * D_ + h * DH_ + d];
    }
    __syncthreads();
    int tx = threadIdx.x & 31, ty = threadIdx.x >> 5;  // col j, base row
    float acc[4] = {0.f, 0.f, 0.f, 0.f};
    for (int d = 0; d < 64; d++) {
        float kv = Ks[tx][d];
#pragma unroll
        for (int rr = 0; rr < 4; rr++) acc[rr] += Qs[ty + 8 * rr][d] * kv;
    }
#pragma unroll
    for (int rr = 0; rr < 4; rr++) {
        int i = i0 + ty + 8 * rr;
        aa[((size_t)bh * I_ + i) * I_ + j0 + tx] = acc[rr];
    }
}

// ---------------- arf[b,h,i,r] = sum_d q2[b,i,h,d]*rel[r,h,d] ---------------
// grid (I/32, B*H)
__global__ __launch_bounds__(256) void arf_kernel(const float* __restrict__ q2,
        const float* __restrict__ rel, float* __restrict__ arf) {
    int bh = blockIdx.y, b = bh >> 4, h = bh & 15;
    int i0 = blockIdx.x * 32;
    __shared__ float Qs[32][65];
    __shared__ float Rs[R_][65];
    for (int e = threadIdx.x; e < 2048; e += 256) {
        int r = e >> 6, d = e & 63;
        Qs[r][d] = q2[((size_t)(b * I_ + i0 + r)) * D_ + h * DH_ + d];
    }
    for (int e = threadIdx.x; e < R_ * 64; e += 256) {
        int r = e >> 6, d = e & 63;
        Rs[r][d] = rel[(size_t)r * D_ + h * DH_ + d];
    }
    __syncthreads();
    for (int o = threadIdx.x; o < 32 * R_; o += 256) {
        int il = o / R_, r = o % R_;
        float s = 0.f;
#pragma unroll
        for (int d = 0; d < 64; d++) s += Qs[il][d] * Rs[r][d];
        arf[((size_t)bh * I_ + i0 + il) * R_ + r] = s;
    }
}

// ---------------- scores = (aa + gather(arf))/8; softmax in place -----------
// one block per (b,h,i) row; rel index = clamp(j-i,-64,64)+64 computed inline
__global__ __launch_bounds__(256) void softmax_kernel(float* __restrict__ a,
        const float* __restrict__ arf) {
    __shared__ float shm[4], shs[4];
    int bhi = blockIdx.x;
    int i = bhi & (I_ - 1);
    float* row = a + (size_t)bhi * I_;
    const float* ar = arf + (size_t)bhi * R_;
    int t = threadIdx.x;
    float4 v = reinterpret_cast<const float4*>(row)[t];
    float vals[4];
#pragma unroll
    for (int c = 0; c < 4; c++) {
        int jj = t * 4 + c;
        int rel = jj - i;
        rel = rel < -64 ? -64 : (rel > 64 ? 64 : rel);
        vals[c] = ((&v.x)[c] + ar[rel + 64]) * 0.125f;
    }
    float m = fmaxf(fmaxf(vals[0], vals[1]), fmaxf(vals[2], vals[3]));
#pragma unroll
    for (int off = 32; off > 0; off >>= 1) m = fmaxf(m, __shfl_down(m, off, 64));
    if ((t & 63) == 0) shm[t >> 6] = m;
    __syncthreads();
    float M = fmaxf(fmaxf(shm[0], shm[1]), fmaxf(shm[2], shm[3]));
    float s = 0.f;
#pragma unroll
    for (int c = 0; c < 4; c++) { vals[c] = expf(vals[c] - M); s += vals[c]; }
#pragma unroll
    for (int off = 32; off > 0; off >>= 1) s += __shfl_down(s, off, 64);
    if ((t & 63) == 0) shs[t >> 6] = s;
    __syncthreads();
    float inv = 1.0f / (shs[0] + shs[1] + shs[2] + shs[3]);
    float4 o;
    o.x = vals[0] * inv; o.y = vals[1] * inv; o.z = vals[2] * inv; o.w = vals[3] * inv;
    reinterpret_cast<float4*>(row)[t] = o;
}

// ---------------- o[b,i,h,d] = (sum_j a[b,h,i,j]*v[b,j,h,d]) * g[b,i,h,d] ---
// grid (I/32, B*H); 32 i-rows x 64 d per block
__global__ __launch_bounds__(256) void pv_gate_kernel(const float* __restrict__ a,
        const float* __restrict__ v, const float* __restrict__ g,
        float* __restrict__ o) {
    int bh = blockIdx.y, b = bh >> 4, h = bh & 15;
    int i0 = blockIdx.x * 32;
    __shared__ float As_[32][33];
    __shared__ float Vs[32][65];
    int tx = threadIdx.x & 63, ty = threadIdx.x >> 6;  // tx = d, ty = row base
    float acc[8] = {};
    for (int k0 = 0; k0 < I_; k0 += 32) {
        for (int e = threadIdx.x; e < 1024; e += 256) {
            int r = e >> 5, k = e & 31;
            As_[r][k] = a[((size_t)bh * I_ + i0 + r) * I_ + k0 + k];
        }
        for (int e = threadIdx.x; e < 2048; e += 256) {
            int k = e >> 6, d = e & 63;
            Vs[k][d] = v[((size_t)(b * I_ + k0 + k)) * D_ + h * DH_ + d];
        }
        __syncthreads();
#pragma unroll
        for (int k = 0; k < 32; k++) {
            float vv = Vs[k][tx];
#pragma unroll
            for (int rr = 0; rr < 8; rr++) acc[rr] += As_[ty + 4 * rr][k] * vv;
        }
        __syncthreads();
    }
#pragma unroll
    for (int rr = 0; rr < 8; rr++) {
        int i = i0 + ty + 4 * rr;
        size_t oi = ((size_t)(b * I_ + i)) * D_ + h * DH_ + tx;
        o[oi] = acc[rr] * g[oi];
    }
}

extern "C" void kernel_launch(void* const* d_in, const int* in_sizes, int n_in,
                              void* d_out, int out_size, void* d_ws, size_t ws_size,
                              hipStream_t stream) {
    const float* x      = (const float*)d_in[0];
    const float* jin    = (const float*)d_in[1];
    const float* ln1_g  = (const float*)d_in[2];
    const float* ln1_b  = (const float*)d_in[3];
    const float* Wv_w   = (const float*)d_in[4];
    const float* Wv_b   = (const float*)d_in[5];
    const float* Wg_w   = (const float*)d_in[6];
    const float* Wg_b   = (const float*)d_in[7];
    const float* lnv_g  = (const float*)d_in[8];
    const float* lnv_b  = (const float*)d_in[9];
    const float* Wq1_w  = (const float*)d_in[10];
    const float* Wq1_b  = (const float*)d_in[11];
    const float* Wk_w   = (const float*)d_in[12];
    const float* Wk_b   = (const float*)d_in[13];
    const float* Wq2_w  = (const float*)d_in[14];
    const float* Wq2_b  = (const float*)d_in[15];
    const float* rel    = (const float*)d_in[16];
    const float* Wo_w   = (const float*)d_in[17];
    const float* Wo_b   = (const float*)d_in[18];
    const float* ln2_g  = (const float*)d_in[19];
    const float* ln2_b  = (const float*)d_in[20];
    const float* ff1_w  = (const float*)d_in[21];
    const float* ff1_b  = (const float*)d_in[22];
    const float* ff2_w  = (const float*)d_in[23];
    const float* ff2_b  = (const float*)d_in[24];
    // d_in[25] = indices: clamp(j-i,-64,64)+64 computed analytically on device

    float* out0  = (float*)d_out;
    float* a_out = out0 + (size_t)B_ * I_ * D_;    // [B,H,I,J] = 32M floats

    const size_t N1 = (size_t)B_ * I_ * D_;        // 2,097,152 floats / slot
    float* w    = (float*)d_ws;
    // slot map (floats): 0:xn 1:v 2:g 3:q1 4:kh 5:q2 6:arf(4.23M)
    // reuse after attention: o->arf slot, x1->q2 slot, x1n->kh slot, h->slots 0-3
    float* xn   = w;
    float* vbuf = w + N1;
    float* gbuf = w + 2 * N1;
    float* q1   = w + 3 * N1;
    float* kh   = w + 4 * N1;
    float* q2   = w + 5 * N1;
    float* arf  = w + 6 * N1;
    float* obuf = w + 6 * N1;   // reuse arf (free after softmax)
    float* x1   = w + 5 * N1;   // reuse q2
    float* x1n  = w + 4 * N1;   // reuse kh
    float* hbuf = w;            // reuse slots 0..3 (8M floats for [2048,4096])
    // total ws use: 6*N1 + 4,227,072 floats = 67.3 MB

    dim3 blk(256);
    ln_kernel<<<MROWS, blk, 0, stream>>>(x, xn, ln1_g, ln1_b);
    gemm_f32<1, 0><<<dim3(16, 32), blk, 0, stream>>>(xn, Wv_w, Wv_b, nullptr, vbuf, MROWS, D_, D_);
    ln_kernel<<<MROWS, blk, 0, stream>>>(vbuf, vbuf, lnv_g, lnv_b);
    gemm_f32<1, 0><<<dim3(16, 32), blk, 0, stream>>>(xn, Wg_w, Wg_b, nullptr, gbuf, MROWS, D_, D_);
    gemm_f32<0, 0><<<dim3(16, 32), blk, 0, stream>>>(jin, Wq1_w, Wq1_b, nullptr, q1, MROWS, D_, D_);
    gemm_f32<0, 0><<<dim3(16, 32), blk, 0, stream>>>(jin, Wk_w, Wk_b, nullptr, kh, MROWS, D_, D_);
    gemm_f32<0, 0><<<dim3(16, 32), blk, 0, stream>>>(jin, Wq2_w, Wq2_b, nullptr, q2, MROWS, D_, D_);
    aa_kernel<<<dim3(32, 32, 32), blk, 0, stream>>>(q1, kh, a_out);
    arf_kernel<<<dim3(32, 32), blk, 0, stream>>>(q2, rel, arf);
    softmax_kernel<<<32768, blk, 0, stream>>>(a_out, arf);
    pv_gate_kernel<<<dim3(32, 32), blk, 0, stream>>>(a_out, vbuf, gbuf, obuf);
    gemm_f32<0, 1><<<dim3(16, 32), blk, 0, stream>>>(obuf, Wo_w, Wo_b, x, x1, MROWS, D_, D_);
    ln_kernel<<<MROWS, blk, 0, stream>>>(x1, x1n, ln2_g, ln2_b);
    gemm_f32<2, 0><<<dim3(64, 32), blk, 0, stream>>>(x1n, ff1_w, ff1_b, nullptr, hbuf, MROWS, FF_, D_);
    gemm_f32<0, 1><<<dim3(16, 32), blk, 0, stream>>>(hbuf, ff2_w, ff2_b, x1, out0, MROWS, D_, FF_);
}

// Round 2
// 739.294 us; speedup vs baseline: 2.3099x; 2.3099x over previous
//
#include <hip/hip_runtime.h>
#include <hip/hip_bf16.h>
#include <math.h>

// PosNetEncoder: B=2, I=J=1024, D=1024, H=16, DH=64, K=64 (R=129), FF=4096
#define D_   1024
#define H_   16
#define DH_  64
#define FF_  4096
#define R_   129
#define I_   1024
#define B_   2
#define MROWS 2048   // B_*I_

typedef __bf16 v8bf16 __attribute__((ext_vector_type(8)));
typedef float f32x4 __attribute__((ext_vector_type(4)));

__device__ __forceinline__ float gelu_f(float x) {
    return 0.5f * x * (1.0f + erff(x * 0.7071067811865476f));
}

__device__ __forceinline__ void ldsld16(const void* g, void* l) {
    __builtin_amdgcn_global_load_lds(
        (const __attribute__((address_space(1))) void*)g,
        (__attribute__((address_space(3))) void*)l, 16, 0, 0);
}

// ---------------- fp32 -> bf16 convert (vector-4) ---------------------------
__global__ __launch_bounds__(256) void cvt_bf16(const float* __restrict__ in,
        __hip_bfloat16* __restrict__ out, int n4) {
    int i = blockIdx.x * 256 + threadIdx.x;
    if (i >= n4) return;
    float4 v = reinterpret_cast<const float4*>(in)[i];
    union { __hip_bfloat16 h[4]; uint2 u; } pk;
    pk.h[0] = __float2bfloat16(v.x); pk.h[1] = __float2bfloat16(v.y);
    pk.h[2] = __float2bfloat16(v.z); pk.h[3] = __float2bfloat16(v.w);
    reinterpret_cast<uint2*>(out)[i] = pk.u;
}

// ---------------- W[K,N] f32 -> WT[N,K] bf16 (64x64 tiles) ------------------
__global__ __launch_bounds__(256) void wtrans(const float* __restrict__ W,
        __hip_bfloat16* __restrict__ WT, int K, int N) {
    __shared__ float T[64][65];
    int k0 = blockIdx.y * 64, n0 = blockIdx.x * 64;
    int t = threadIdx.x;
#pragma unroll
    for (int i = 0; i < 16; i++) {
        int e = t + i * 256, r = e >> 6, c = e & 63;
        T[r][c] = W[(size_t)(k0 + r) * N + n0 + c];
    }
    __syncthreads();
#pragma unroll
    for (int i = 0; i < 16; i++) {
        int e = t + i * 256, r = e >> 6, c = e & 63;
        WT[(size_t)(n0 + r) * K + k0 + c] = __float2bfloat16(T[c][r]);
    }
}

// ---------------- MFMA bf16 GEMM: C = epi(A[M,K] @ Bt[N,K]^T) ---------------
// 128x128 tile, BK=64, 4 waves (2x2), 16x16x32 MFMA, global_load_lds staging
// with XOR slot swizzle (slot = kb ^ (row&7)) -> conflict-free ds_read_b128.
// ACT: 0 none 1 gelu 2 relu. RES: += res. OUTBF: bf16 out. GATHER: aa epilogue.
template<int ACT, int RES, int OUTBF, int GATHER>
__global__ __launch_bounds__(256) void gemm_mfma(
        const __hip_bfloat16* __restrict__ A,
        const __hip_bfloat16* __restrict__ Bt,
        const float* __restrict__ bias,
        const float* __restrict__ res,
        void* __restrict__ Cout,
        const float* __restrict__ arf,
        int N, int Kd, int lda, int ldb, int ldc,
        size_t sAb, size_t sAh, size_t sBb, size_t sBh, size_t sCz) {
    __shared__ __align__(16) __hip_bfloat16 As[128 * 64];
    __shared__ __align__(16) __hip_bfloat16 Bs[128 * 64];
    const char* AsB = (const char*)As;
    const char* BsB = (const char*)Bs;
    int z = blockIdx.z;
    const __hip_bfloat16* Ab = A + (size_t)(z >> 4) * sAb + (size_t)(z & 15) * sAh;
    const __hip_bfloat16* Bb = Bt + (size_t)(z >> 4) * sBb + (size_t)(z & 15) * sBh;
    float* Cf = (float*)Cout + (size_t)z * sCz;
    __hip_bfloat16* Cb = (__hip_bfloat16*)Cout + (size_t)z * sCz;
    const float* arfz = arf + (size_t)z * I_ * R_;
    int m0 = blockIdx.y * 128, n0 = blockIdx.x * 128;
    int t = threadIdx.x;
    int l = t & 63, w = t >> 6;
    int wr = w >> 1, wc = w & 1;
    int lr = l & 15, kq = l >> 4;
    int rx = lr & 7;   // row&7 for all frag rows (row = 16a + lr)

    f32x4 acc[4][4] = {};

    for (int k0 = 0; k0 < Kd; k0 += 64) {
#pragma unroll
        for (int i = 0; i < 4; i++) {
            int e = t + i * 256;
            int row = e >> 3, sl = e & 7;
            int kb = sl ^ (row & 7);
            ldsld16(Ab + (size_t)(m0 + row) * lda + (k0 + kb * 8), (void*)(AsB + e * 16));
        }
#pragma unroll
        for (int i = 0; i < 4; i++) {
            int e = t + i * 256;
            int row = e >> 3, sl = e & 7;
            int kb = sl ^ (row & 7);
            int nr = n0 + row; if (nr > N - 1) nr = N - 1;   // tail tile (arf N=129)
            ldsld16(Bb + (size_t)nr * ldb + (k0 + kb * 8), (void*)(BsB + e * 16));
        }
        __syncthreads();
#pragma unroll
        for (int kc = 0; kc < 2; kc++) {
            int sloff = (((kc << 2) + kq) ^ rx) << 4;
            v8bf16 af[4], bfr[4];
#pragma unroll
            for (int mr = 0; mr < 4; mr++)
                af[mr] = *(const v8bf16*)(AsB + ((wr * 64 + mr * 16 + lr) << 7) + sloff);
#pragma unroll
            for (int nc = 0; nc < 4; nc++)
                bfr[nc] = *(const v8bf16*)(BsB + ((wc * 64 + nc * 16 + lr) << 7) + sloff);
#pragma unroll
            for (int mr = 0; mr < 4; mr++)
#pragma unroll
                for (int nc = 0; nc < 4; nc++)
                    acc[mr][nc] = __builtin_amdgcn_mfma_f32_16x16x32_bf16(
                        af[mr], bfr[nc], acc[mr][nc], 0, 0, 0);
        }
        __syncthreads();
    }

    // epilogue: C row = m0 + wr*64 + mr*16 + (l>>4)*4 + ri ; col = n0 + wc*64 + nc*16 + lr
#pragma unroll
    for (int mr = 0; mr < 4; mr++) {
        int rbase = m0 + wr * 64 + mr * 16 + kq * 4;
#pragma unroll
        for (int nc = 0; nc < 4; nc++) {
            int col = n0 + wc * 64 + nc * 16 + lr;
            bool okc = col < N;
            float bv = (bias && okc) ? bias[col] : 0.f;
#pragma unroll
            for (int ri = 0; ri < 4; ri++) {
                int r = rbase + ri;
                float val = acc[mr][nc][ri] + bv;
                if (ACT == 1) val = gelu_f(val);
                if (ACT == 2) val = fmaxf(val, 0.f);
                if (GATHER) {
                    int rel = col - r;
                    rel = rel < -64 ? -64 : (rel > 64 ? 64 : rel);
                    val = (val + arfz[(size_t)r * R_ + rel + 64]) * 0.125f;
                }
                if (RES) val += res[(size_t)r * ldc + col];
                if (okc) {
                    if (OUTBF) Cb[(size_t)r * ldc + col] = __float2bfloat16(val);
                    else       Cf[(size_t)r * ldc + col] = val;
                }
            }
        }
    }
}

// ---------------- LayerNorm rows of 1024 (256 thr, float4) ------------------
template<int OUTBF>
__global__ __launch_bounds__(256) void ln_kernel(const float* __restrict__ in,
        void* __restrict__ out, const float* __restrict__ gw,
        const float* __restrict__ bw) {
    __shared__ float shs[4], shq[4];
    int row = blockIdx.x;
    int t = threadIdx.x;
    float4 v = reinterpret_cast<const float4*>(in + (size_t)row * D_)[t];
    float s = v.x + v.y + v.z + v.w;
#pragma unroll
    for (int off = 32; off > 0; off >>= 1) s += __shfl_down(s, off, 64);
    if ((t & 63) == 0) shs[t >> 6] = s;
    __syncthreads();
    float mean = (shs[0] + shs[1] + shs[2] + shs[3]) * (1.0f / D_);
    float d0 = v.x - mean, d1 = v.y - mean, d2 = v.z - mean, d3 = v.w - mean;
    float q = d0 * d0 + d1 * d1 + d2 * d2 + d3 * d3;
#pragma unroll
    for (int off = 32; off > 0; off >>= 1) q += __shfl_down(q, off, 64);
    if ((t & 63) == 0) shq[t >> 6] = q;
    __syncthreads();
    float var = (shq[0] + shq[1] + shq[2] + shq[3]) * (1.0f / D_);
    float rstd = rsqrtf(var + 1e-5f);
    float4 g4 = reinterpret_cast<const float4*>(gw)[t];
    float4 b4 = reinterpret_cast<const float4*>(bw)[t];
    float o0 = d0 * rstd * g4.x + b4.x;
    float o1 = d1 * rstd * g4.y + b4.y;
    float o2 = d2 * rstd * g4.z + b4.z;
    float o3 = d3 * rstd * g4.w + b4.w;
    if (OUTBF) {
        union { __hip_bfloat16 h[4]; uint2 u; } pk;
        pk.h[0] = __float2bfloat16(o0); pk.h[1] = __float2bfloat16(o1);
        pk.h[2] = __float2bfloat16(o2); pk.h[3] = __float2bfloat16(o3);
        reinterpret_cast<uint2*>((__hip_bfloat16*)out + (size_t)row * D_)[t] = pk.u;
    } else {
        float4 o; o.x = o0; o.y = o1; o.z = o2; o.w = o3;
        reinterpret_cast<float4*>((float*)out + (size_t)row * D_)[t] = o;
    }
}

// ---------------- softmax in place (scores already scaled+gathered) ---------
__global__ __launch_bounds__(256) void softmax_kernel(float* __restrict__ a) {
    __shared__ float shm[4], shs[4];
    int bhi = blockIdx.x;
    float* row = a + (size_t)bhi * I_;
    int t = threadIdx.x;
    float4 v = reinterpret_cast<const float4*>(row)[t];
    float vals[4] = {v.x, v.y, v.z, v.w};
    float m = fmaxf(fmaxf(vals[0], vals[1]), fmaxf(vals[2], vals[3]));
#pragma unroll
    for (int off = 32; off > 0; off >>= 1) m = fmaxf(m, __shfl_down(m, off, 64));
    if ((t & 63) == 0) shm[t >> 6] = m;
    __syncthreads();
    float M = fmaxf(fmaxf(shm[0], shm[1]), fmaxf(shm[2], shm[3]));
    float s = 0.f;
#pragma unroll
    for (int c = 0; c < 4; c++) { vals[c] = expf(vals[c] - M); s += vals[c]; }
#pragma unroll
    for (int off = 32; off > 0; off >>= 1) s += __shfl_down(s, off, 64);
    if ((t & 63) == 0) shs[t >> 6] = s;
    __syncthreads();
    float inv = 1.0f / (shs[0] + shs[1] + shs[2] + shs[3]);
    float4 o;
    o.x = vals[0] * inv; o.y = vals[1] * inv; o.z = vals[2] * inv; o.w = vals[3] * inv;
    reinterpret_cast<float4*>(row)[t] = o;
}

// ---------------- o = (a @ v) * g  -> bf16 ----------------------------------
__global__ __launch_bounds__(256) void pv_gate_kernel(const float* __restrict__ a,
        const float* __restrict__ v, const float* __restrict__ g,
        __hip_bfloat16* __restrict__ o) {
    int bh = blockIdx.y, b = bh >> 4, h = bh & 15;
    int i0 = blockIdx.x * 32;
    __shared__ float As_[32][33];
    __shared__ float Vs[32][65];
    int tx = threadIdx.x & 63, ty = threadIdx.x >> 6;
    float acc[8] = {};
    for (int k0 = 0; k0 < I_; k0 += 32) {
        for (int e = threadIdx.x; e < 1024; e += 256) {
            int r = e >> 5, k = e & 31;
            As_[r][k] = a[((size_t)bh * I_ + i0 + r) * I_ + k0 + k];
        }
        for (int e = threadIdx.x; e < 2048; e += 256) {
            int k = e >> 6, d = e & 63;
            Vs[k][d] = v[((size_t)(b * I_ + k0 + k)) * D_ + h * DH_ + d];
        }
        __syncthreads();
#pragma unroll
        for (int k = 0; k < 32; k++) {
            float vv = Vs[k][tx];
#pragma unroll
            for (int rr = 0; rr < 8; rr++) acc[rr] += As_[ty + 4 * rr][k] * vv;
        }
        __syncthreads();
    }
#pragma unroll
    for (int rr = 0; rr < 8; rr++) {
        int i = i0 + ty + 4 * rr;
        size_t oi = ((size_t)(b * I_ + i)) * D_ + h * DH_ + tx;
        o[oi] = __float2bfloat16(acc[rr] * g[oi]);
    }
}

extern "C" void kernel_launch(void* const* d_in, const int* in_sizes, int n_in,
                              void* d_out, int out_size, void* d_ws, size_t ws_size,
                              hipStream_t stream) {
    const float* x      = (const float*)d_in[0];
    const float* jin    = (const float*)d_in[1];
    const float* ln1_g  = (const float*)d_in[2];
    const float* ln1_b  = (const float*)d_in[3];
    const float* Wv_w   = (const float*)d_in[4];
    const float* Wv_b   = (const float*)d_in[5];
    const float* Wg_w   = (const float*)d_in[6];
    const float* Wg_b   = (const float*)d_in[7];
    const float* lnv_g  = (const float*)d_in[8];
    const float* lnv_b  = (const float*)d_in[9];
    const float* Wq1_w  = (const float*)d_in[10];
    const float* Wq1_b  = (const float*)d_in[11];
    const float* Wk_w   = (const float*)d_in[12];
    const float* Wk_b   = (const float*)d_in[13];
    const float* Wq2_w  = (const float*)d_in[14];
    const float* Wq2_b  = (const float*)d_in[15];
    const float* rel    = (const float*)d_in[16];
    const float* Wo_w   = (const float*)d_in[17];
    const float* Wo_b   = (const float*)d_in[18];
    const float* ln2_g  = (const float*)d_in[19];
    const float* ln2_b  = (const float*)d_in[20];
    const float* ff1_w  = (const float*)d_in[21];
    const float* ff1_b  = (const float*)d_in[22];
    const float* ff2_w  = (const float*)d_in[23];
    const float* ff2_b  = (const float*)d_in[24];
    // d_in[25] = indices: computed analytically on device

    float* out0  = (float*)d_out;
    float* a_out = out0 + (size_t)B_ * I_ * D_;    // [B,H,I,J]

    char* wsb = (char*)d_ws;
    const size_t MB = 1u << 20;
    // persistent bf16 transposed weights [0,28MB)
    __hip_bfloat16* WvT  = (__hip_bfloat16*)(wsb + 0 * MB);
    __hip_bfloat16* WgT  = (__hip_bfloat16*)(wsb + 2 * MB);
    __hip_bfloat16* Wq1T = (__hip_bfloat16*)(wsb + 4 * MB);
    __hip_bfloat16* WkT  = (__hip_bfloat16*)(wsb + 6 * MB);
    __hip_bfloat16* Wq2T = (__hip_bfloat16*)(wsb + 8 * MB);
    __hip_bfloat16* WoT  = (__hip_bfloat16*)(wsb + 10 * MB);
    __hip_bfloat16* ff1T = (__hip_bfloat16*)(wsb + 12 * MB);  // [4096,1024] 8MB
    __hip_bfloat16* ff2T = (__hip_bfloat16*)(wsb + 20 * MB);  // [1024,4096] 8MB
    // activations (slot-reused; peak 64.9MB, Round-1 proved >=67.3MB available)
    __hip_bfloat16* jbf  = (__hip_bfloat16*)(wsb + 28 * MB);
    __hip_bfloat16* q1b  = (__hip_bfloat16*)(wsb + 32 * MB);
    __hip_bfloat16* khb  = (__hip_bfloat16*)(wsb + 36 * MB);
    __hip_bfloat16* q2b  = (__hip_bfloat16*)(wsb + 40 * MB);
    __hip_bfloat16* relb = (__hip_bfloat16*)(wsb + 44 * MB);  // 0.26MB
    float*          arf  = (float*)        (wsb + 48 * MB);   // 16.9MB, dead after aa
    __hip_bfloat16* xnb  = (__hip_bfloat16*)(wsb + 32 * MB);  // reuse q1b
    float*          vbuf = (float*)        (wsb + 36 * MB);   // reuse khb/q2b
    float*          gbuf = (float*)        (wsb + 44 * MB);   // reuse relb/arf-head
    __hip_bfloat16* obuf = (__hip_bfloat16*)(wsb + 52 * MB);
    float*          x1   = (float*)        (wsb + 56 * MB);
    __hip_bfloat16* x1nb = (__hip_bfloat16*)(wsb + 32 * MB);
    __hip_bfloat16* hbuf = (__hip_bfloat16*)(wsb + 36 * MB);  // 16MB

    dim3 blk(256);
    const size_t M1 = (size_t)I_ * D_;  // per-batch A stride (1M elems)

    // input converts + weight transposes
    cvt_bf16<<<2048, blk, 0, stream>>>(jin, jbf, (MROWS * D_) / 4);
    cvt_bf16<<<129, blk, 0, stream>>>(rel, relb, (R_ * D_) / 4);
    wtrans<<<dim3(16, 16), blk, 0, stream>>>(Wv_w, WvT, D_, D_);
    wtrans<<<dim3(16, 16), blk, 0, stream>>>(Wg_w, WgT, D_, D_);
    wtrans<<<dim3(16, 16), blk, 0, stream>>>(Wq1_w, Wq1T, D_, D_);
    wtrans<<<dim3(16, 16), blk, 0, stream>>>(Wk_w, WkT, D_, D_);
    wtrans<<<dim3(16, 16), blk, 0, stream>>>(Wq2_w, Wq2T, D_, D_);
    wtrans<<<dim3(16, 16), blk, 0, stream>>>(Wo_w, WoT, D_, D_);
    wtrans<<<dim3(64, 16), blk, 0, stream>>>(ff1_w, ff1T, D_, FF_);
    wtrans<<<dim3(16, 64), blk, 0, stream>>>(ff2_w, ff2T, FF_, D_);

    // q1/k/q2 projections (bf16 out, head-major rows)
    gemm_mfma<0, 0, 1, 0><<<dim3(8, 16, 1), blk, 0, stream>>>(
        jbf, Wq1T, Wq1_b, nullptr, q1b, arf, D_, D_, D_, D_, D_, 0, 0, 0, 0, 0);
    gemm_mfma<0, 0, 1, 0><<<dim3(8, 16, 1), blk, 0, stream>>>(
        jbf, WkT, Wk_b, nullptr, khb, arf, D_, D_, D_, D_, D_, 0, 0, 0, 0, 0);
    gemm_mfma<0, 0, 1, 0><<<dim3(8, 16, 1), blk, 0, stream>>>(
        jbf, Wq2T, Wq2_b, nullptr, q2b, arf, D_, D_, D_, D_, D_, 0, 0, 0, 0, 0);
    // arf[bh,i,r] = q2 . rel  (batched over bh via strides)
    gemm_mfma<0, 0, 0, 0><<<dim3(2, 8, 32), blk, 0, stream>>>(
        q2b, relb, nullptr, nullptr, arf, arf,
        R_, DH_, D_, D_, R_, M1, (size_t)DH_, 0, (size_t)DH_, (size_t)I_ * R_);
    // aa + gathered arf + scale -> a_out scores
    gemm_mfma<0, 0, 0, 1><<<dim3(8, 8, 32), blk, 0, stream>>>(
        q1b, khb, nullptr, nullptr, a_out, arf,
        I_, DH_, D_, D_, I_, M1, (size_t)DH_, M1, (size_t)DH_, (size_t)I_ * I_);
    softmax_kernel<<<32768, blk, 0, stream>>>(a_out);

    // value/gate streams
    ln_kernel<1><<<MROWS, blk, 0, stream>>>(x, xnb, ln1_g, ln1_b);
    gemm_mfma<1, 0, 0, 0><<<dim3(8, 16, 1), blk, 0, stream>>>(
        xnb, WvT, Wv_b, nullptr, vbuf, arf, D_, D_, D_, D_, D_, 0, 0, 0, 0, 0);
    ln_kernel<0><<<MROWS, blk, 0, stream>>>(vbuf, vbuf, lnv_g, lnv_b);
    gemm_mfma<1, 0, 0, 0><<<dim3(8, 16, 1), blk, 0, stream>>>(
        xnb, WgT, Wg_b, nullptr, gbuf, arf, D_, D_, D_, D_, D_, 0, 0, 0, 0, 0);
    pv_gate_kernel<<<dim3(32, 32), blk, 0, stream>>>(a_out, vbuf, gbuf, obuf);

    // output projection + residual, FF block
    gemm_mfma<0, 1, 0, 0><<<dim3(8, 16, 1), blk, 0, stream>>>(
        obuf, WoT, Wo_b, x, x1, arf, D_, D_, D_, D_, D_, 0, 0, 0, 0, 0);
    ln_kernel<1><<<MROWS, blk, 0, stream>>>(x1, x1nb, ln2_g, ln2_b);
    gemm_mfma<2, 0, 1, 0><<<dim3(32, 16, 1), blk, 0, stream>>>(
        x1nb, ff1T, ff1_b, nullptr, hbuf, arf, FF_, D_, D_, D_, FF_, 0, 0, 0, 0, 0);
    gemm_mfma<0, 1, 0, 0><<<dim3(8, 16, 1), blk, 0, stream>>>(
        hbuf, ff2T, ff2_b, x1, out0, arf, D_, FF_, FF_, FF_, D_, 0, 0, 0, 0, 0);
}

// Round 3
// 387.886 us; speedup vs baseline: 4.4026x; 1.9060x over previous
//
#include <hip/hip_runtime.h>
#include <hip/hip_bf16.h>
#include <math.h>

// PosNetEncoder: B=2, I=J=1024, D=1024, H=16, DH=64, K=64 (R=129), FF=4096
#define D_   1024
#define H_   16
#define DH_  64
#define FF_  4096
#define R_   129
#define I_   1024
#define B_   2
#define MROWS 2048   // B_*I_

typedef __bf16 v8bf16 __attribute__((ext_vector_type(8)));
typedef float f32x4 __attribute__((ext_vector_type(4)));

__device__ __forceinline__ float gelu_f(float x) {
    return 0.5f * x * (1.0f + erff(x * 0.7071067811865476f));
}

__device__ __forceinline__ void ldsld16(const void* g, void* l) {
    __builtin_amdgcn_global_load_lds(
        (const __attribute__((address_space(1))) void*)g,
        (__attribute__((address_space(3))) void*)l, 16, 0, 0);
}

// ---------------- fp32 -> bf16 convert (vector-4) ---------------------------
__global__ __launch_bounds__(256) void cvt_bf16(const float* __restrict__ in,
        __hip_bfloat16* __restrict__ out, int n4) {
    int i = blockIdx.x * 256 + threadIdx.x;
    if (i >= n4) return;
    float4 v = reinterpret_cast<const float4*>(in)[i];
    union { __hip_bfloat16 h[4]; uint2 u; } pk;
    pk.h[0] = __float2bfloat16(v.x); pk.h[1] = __float2bfloat16(v.y);
    pk.h[2] = __float2bfloat16(v.z); pk.h[3] = __float2bfloat16(v.w);
    reinterpret_cast<uint2*>(out)[i] = pk.u;
}

// ---------------- W[K,N] f32 -> WT[N,K] bf16 (64x64 tiles) ------------------
__global__ __launch_bounds__(256) void wtrans(const float* __restrict__ W,
        __hip_bfloat16* __restrict__ WT, int K, int N) {
    __shared__ float T[64][65];
    int k0 = blockIdx.y * 64, n0 = blockIdx.x * 64;
    int t = threadIdx.x;
#pragma unroll
    for (int i = 0; i < 16; i++) {
        int e = t + i * 256, r = e >> 6, c = e & 63;
        T[r][c] = W[(size_t)(k0 + r) * N + n0 + c];
    }
    __syncthreads();
#pragma unroll
    for (int i = 0; i < 16; i++) {
        int e = t + i * 256, r = e >> 6, c = e & 63;
        WT[(size_t)(n0 + r) * K + k0 + c] = __float2bfloat16(T[c][r]);
    }
}

// ---- v[b,j,h,d] fp32 -> vt[b,h,d,j] bf16 (64x64 tiles) ---------------------
__global__ __launch_bounds__(256) void vtrans(const float* __restrict__ v,
        __hip_bfloat16* __restrict__ vt) {
    __shared__ float T[64][65];
    int z = blockIdx.y, b = z >> 4, h = z & 15;
    int j0 = blockIdx.x * 64;
    int t = threadIdx.x;
#pragma unroll
    for (int i = 0; i < 16; i++) {
        int e = t + i * 256, r = e >> 6, c = e & 63;   // r=j, c=d
        T[r][c] = v[(size_t)(b * I_ + j0 + r) * D_ + h * DH_ + c];
    }
    __syncthreads();
#pragma unroll
    for (int i = 0; i < 16; i++) {
        int e = t + i * 256, r = e >> 6, c = e & 63;   // r=d, c=j
        vt[((size_t)z * DH_ + r) * I_ + j0 + c] = __float2bfloat16(T[c][r]);
    }
}

// ---------------- MFMA bf16 GEMM: C = epi(A[M,K] @ Bt[N,K]^T) ---------------
// Tile BM=MR*32 x 128, BK=64, 4 waves, 16x16x32 MFMA, global_load_lds staging
// with XOR slot swizzle (slot = kb ^ (row&7)) -> conflict-free ds_read_b128.
// ACT: 0 none 1 gelu 2 relu. RES: += res. OUTBF: bf16 out. GATHER: aa epilogue.
template<int MR, int ACT, int RES, int OUTBF, int GATHER>
__global__ __launch_bounds__(256) void gemm_mfma(
        const __hip_bfloat16* __restrict__ A,
        const __hip_bfloat16* __restrict__ Bt,
        const float* __restrict__ bias,
        const float* __restrict__ res,
        void* __restrict__ Cout,
        const float* __restrict__ arf,
        int N, int Kd, int lda, int ldb, int ldc,
        size_t sAb, size_t sAh, size_t sBb, size_t sBh, size_t sCz) {
    __shared__ __align__(16) __hip_bfloat16 As[MR * 32 * 64];
    __shared__ __align__(16) __hip_bfloat16 Bs[128 * 64];
    const char* AsB = (const char*)As;
    const char* BsB = (const char*)Bs;
    int z = blockIdx.z;
    const __hip_bfloat16* Ab = A + (size_t)(z >> 4) * sAb + (size_t)(z & 15) * sAh;
    const __hip_bfloat16* Bb = Bt + (size_t)(z >> 4) * sBb + (size_t)(z & 15) * sBh;
    float* Cf = (float*)Cout + (size_t)z * sCz;
    __hip_bfloat16* Cb = (__hip_bfloat16*)Cout + (size_t)z * sCz;
    const float* arfz = arf + (size_t)z * I_ * R_;
    int m0 = blockIdx.y * (MR * 32), n0 = blockIdx.x * 128;
    int t = threadIdx.x;
    int l = t & 63, w = t >> 6;
    int wr = w >> 1, wc = w & 1;
    int lr = l & 15, kq = l >> 4;
    int rx = lr & 7;

    f32x4 acc[MR][4] = {};

    for (int k0 = 0; k0 < Kd; k0 += 64) {
#pragma unroll
        for (int i = 0; i < MR; i++) {
            int e = t + i * 256;
            int row = e >> 3, sl = e & 7;
            int kb = sl ^ (row & 7);
            ldsld16(Ab + (size_t)(m0 + row) * lda + (k0 + kb * 8), (void*)(AsB + e * 16));
        }
#pragma unroll
        for (int i = 0; i < 4; i++) {
            int e = t + i * 256;
            int row = e >> 3, sl = e & 7;
            int kb = sl ^ (row & 7);
            int nr = n0 + row; if (nr > N - 1) nr = N - 1;   // tail tile (arf N=129)
            ldsld16(Bb + (size_t)nr * ldb + (k0 + kb * 8), (void*)(BsB + e * 16));
        }
        __syncthreads();
#pragma unroll
        for (int kc = 0; kc < 2; kc++) {
            int sloff = (((kc << 2) + kq) ^ rx) << 4;
            v8bf16 af[MR], bfr[4];
#pragma unroll
            for (int mr = 0; mr < MR; mr++)
                af[mr] = *(const v8bf16*)(AsB + ((wr * (MR * 16) + mr * 16 + lr) << 7) + sloff);
#pragma unroll
            for (int nc = 0; nc < 4; nc++)
                bfr[nc] = *(const v8bf16*)(BsB + ((wc * 64 + nc * 16 + lr) << 7) + sloff);
#pragma unroll
            for (int mr = 0; mr < MR; mr++)
#pragma unroll
                for (int nc = 0; nc < 4; nc++)
                    acc[mr][nc] = __builtin_amdgcn_mfma_f32_16x16x32_bf16(
                        af[mr], bfr[nc], acc[mr][nc], 0, 0, 0);
        }
        __syncthreads();
    }

#pragma unroll
    for (int mr = 0; mr < MR; mr++) {
        int rbase = m0 + wr * (MR * 16) + mr * 16 + kq * 4;
#pragma unroll
        for (int nc = 0; nc < 4; nc++) {
            int col = n0 + wc * 64 + nc * 16 + lr;
            bool okc = col < N;
            float bv = (bias && okc) ? bias[col] : 0.f;
#pragma unroll
            for (int ri = 0; ri < 4; ri++) {
                int r = rbase + ri;
                float val = acc[mr][nc][ri] + bv;
                if (ACT == 1) val = gelu_f(val);
                if (ACT == 2) val = fmaxf(val, 0.f);
                if (GATHER) {
                    int rel = col - r;
                    rel = rel < -64 ? -64 : (rel > 64 ? 64 : rel);
                    val = (val + arfz[(size_t)r * R_ + rel + 64]) * 0.125f;
                }
                if (RES) val += res[(size_t)r * ldc + col];
                if (okc) {
                    if (OUTBF) Cb[(size_t)r * ldc + col] = __float2bfloat16(val);
                    else       Cf[(size_t)r * ldc + col] = val;
                }
            }
        }
    }
}

// ---------------- PV: o[b,i,hd] = (sum_j a[bh,i,j] * vt[bh,d,j]) * g --------
// batched over z=bh. A (fp32) reg-staged -> bf16 LDS; B via global_load_lds.
// 128 rows x 64 cols per block; 4 waves each 32 rows x 64 cols.
__global__ __launch_bounds__(256) void pv_mfma(const float* __restrict__ a,
        const __hip_bfloat16* __restrict__ vt, const float* __restrict__ g,
        __hip_bfloat16* __restrict__ o) {
    __shared__ __align__(16) __hip_bfloat16 As[128 * 64];
    __shared__ __align__(16) __hip_bfloat16 Bs[64 * 64];
    char* AsB = (char*)As;
    const char* BsB = (const char*)Bs;
    int z = blockIdx.z, b = z >> 4, h = z & 15;
    const float* Ab = a + (size_t)z * I_ * I_;
    const __hip_bfloat16* Bb = vt + (size_t)z * DH_ * I_;
    int i0 = blockIdx.x * 128;
    int t = threadIdx.x, l = t & 63, w = t >> 6;
    int lr = l & 15, kq = l >> 4, rx = lr & 7;
    f32x4 acc[2][4] = {};
    for (int k0 = 0; k0 < I_; k0 += 64) {
#pragma unroll
        for (int i = 0; i < 2; i++) {          // stage V^T rows (d)
            int e = t + i * 256;
            int row = e >> 3, sl = e & 7;
            int kb = sl ^ (row & 7);
            ldsld16(Bb + (size_t)row * I_ + k0 + kb * 8, (void*)(BsB + e * 16));
        }
#pragma unroll
        for (int i = 0; i < 4; i++) {          // reg-stage a fp32 -> bf16
            int e = t + i * 256;
            int row = e >> 3, sl = e & 7;
            int kb = sl ^ (row & 7);
            const float* src = Ab + (size_t)(i0 + row) * I_ + k0 + kb * 8;
            float4 f0 = *(const float4*)src;
            float4 f1 = *(const float4*)(src + 4);
            union { __hip_bfloat16 hh[8]; uint4 u; } pk;
            pk.hh[0] = __float2bfloat16(f0.x); pk.hh[1] = __float2bfloat16(f0.y);
            pk.hh[2] = __float2bfloat16(f0.z); pk.hh[3] = __float2bfloat16(f0.w);
            pk.hh[4] = __float2bfloat16(f1.x); pk.hh[5] = __float2bfloat16(f1.y);
            pk.hh[6] = __float2bfloat16(f1.z); pk.hh[7] = __float2bfloat16(f1.w);
            *(uint4*)(AsB + e * 16) = pk.u;
        }
        __syncthreads();
#pragma unroll
        for (int kc = 0; kc < 2; kc++) {
            int sloff = (((kc << 2) + kq) ^ rx) << 4;
            v8bf16 af[2], bfr[4];
#pragma unroll
            for (int mr = 0; mr < 2; mr++)
                af[mr] = *(const v8bf16*)(AsB + ((w * 32 + mr * 16 + lr) << 7) + sloff);
#pragma unroll
            for (int nc = 0; nc < 4; nc++)
                bfr[nc] = *(const v8bf16*)(BsB + ((nc * 16 + lr) << 7) + sloff);
#pragma unroll
            for (int mr = 0; mr < 2; mr++)
#pragma unroll
                for (int nc = 0; nc < 4; nc++)
                    acc[mr][nc] = __builtin_amdgcn_mfma_f32_16x16x32_bf16(
                        af[mr], bfr[nc], acc[mr][nc], 0, 0, 0);
        }
        __syncthreads();
    }
#pragma unroll
    for (int mr = 0; mr < 2; mr++) {
#pragma unroll
        for (int nc = 0; nc < 4; nc++) {
#pragma unroll
            for (int ri = 0; ri < 4; ri++) {
                int r = i0 + w * 32 + mr * 16 + kq * 4 + ri;
                size_t oi = ((size_t)(b * I_ + r)) * D_ + h * DH_ + nc * 16 + lr;
                o[oi] = __float2bfloat16(acc[mr][nc][ri] * g[oi]);
            }
        }
    }
}

// ---------------- LayerNorm rows of 1024 (256 thr, float4) ------------------
template<int OUTBF>
__global__ __launch_bounds__(256) void ln_kernel(const float* __restrict__ in,
        void* __restrict__ out, const float* __restrict__ gw,
        const float* __restrict__ bw) {
    __shared__ float shs[4], shq[4];
    int row = blockIdx.x;
    int t = threadIdx.x;
    float4 v = reinterpret_cast<const float4*>(in + (size_t)row * D_)[t];
    float s = v.x + v.y + v.z + v.w;
#pragma unroll
    for (int off = 32; off > 0; off >>= 1) s += __shfl_down(s, off, 64);
    if ((t & 63) == 0) shs[t >> 6] = s;
    __syncthreads();
    float mean = (shs[0] + shs[1] + shs[2] + shs[3]) * (1.0f / D_);
    float d0 = v.x - mean, d1 = v.y - mean, d2 = v.z - mean, d3 = v.w - mean;
    float q = d0 * d0 + d1 * d1 + d2 * d2 + d3 * d3;
#pragma unroll
    for (int off = 32; off > 0; off >>= 1) q += __shfl_down(q, off, 64);
    if ((t & 63) == 0) shq[t >> 6] = q;
    __syncthreads();
    float var = (shq[0] + shq[1] + shq[2] + shq[3]) * (1.0f / D_);
    float rstd = rsqrtf(var + 1e-5f);
    float4 g4 = reinterpret_cast<const float4*>(gw)[t];
    float4 b4 = reinterpret_cast<const float4*>(bw)[t];
    float o0 = d0 * rstd * g4.x + b4.x;
    float o1 = d1 * rstd * g4.y + b4.y;
    float o2 = d2 * rstd * g4.z + b4.z;
    float o3 = d3 * rstd * g4.w + b4.w;
    if (OUTBF) {
        union { __hip_bfloat16 h[4]; uint2 u; } pk;
        pk.h[0] = __float2bfloat16(o0); pk.h[1] = __float2bfloat16(o1);
        pk.h[2] = __float2bfloat16(o2); pk.h[3] = __float2bfloat16(o3);
        reinterpret_cast<uint2*>((__hip_bfloat16*)out + (size_t)row * D_)[t] = pk.u;
    } else {
        float4 o; o.x = o0; o.y = o1; o.z = o2; o.w = o3;
        reinterpret_cast<float4*>((float*)out + (size_t)row * D_)[t] = o;
    }
}

// ---------------- softmax in place (scores already scaled+gathered) ---------
__global__ __launch_bounds__(256) void softmax_kernel(float* __restrict__ a) {
    __shared__ float shm[4], shs[4];
    int bhi = blockIdx.x;
    float* row = a + (size_t)bhi * I_;
    int t = threadIdx.x;
    float4 v = reinterpret_cast<const float4*>(row)[t];
    float vals[4] = {v.x, v.y, v.z, v.w};
    float m = fmaxf(fmaxf(vals[0], vals[1]), fmaxf(vals[2], vals[3]));
#pragma unroll
    for (int off = 32; off > 0; off >>= 1) m = fmaxf(m, __shfl_down(m, off, 64));
    if ((t & 63) == 0) shm[t >> 6] = m;
    __syncthreads();
    float M = fmaxf(fmaxf(shm[0], shm[1]), fmaxf(shm[2], shm[3]));
    float s = 0.f;
#pragma unroll
    for (int c = 0; c < 4; c++) { vals[c] = expf(vals[c] - M); s += vals[c]; }
#pragma unroll
    for (int off = 32; off > 0; off >>= 1) s += __shfl_down(s, off, 64);
    if ((t & 63) == 0) shs[t >> 6] = s;
    __syncthreads();
    float inv = 1.0f / (shs[0] + shs[1] + shs[2] + shs[3]);
    float4 o;
    o.x = vals[0] * inv; o.y = vals[1] * inv; o.z = vals[2] * inv; o.w = vals[3] * inv;
    reinterpret_cast<float4*>(row)[t] = o;
}

extern "C" void kernel_launch(void* const* d_in, const int* in_sizes, int n_in,
                              void* d_out, int out_size, void* d_ws, size_t ws_size,
                              hipStream_t stream) {
    const float* x      = (const float*)d_in[0];
    const float* jin    = (const float*)d_in[1];
    const float* ln1_g  = (const float*)d_in[2];
    const float* ln1_b  = (const float*)d_in[3];
    const float* Wv_w   = (const float*)d_in[4];
    const float* Wv_b   = (const float*)d_in[5];
    const float* Wg_w   = (const float*)d_in[6];
    const float* Wg_b   = (const float*)d_in[7];
    const float* lnv_g  = (const float*)d_in[8];
    const float* lnv_b  = (const float*)d_in[9];
    const float* Wq1_w  = (const float*)d_in[10];
    const float* Wq1_b  = (const float*)d_in[11];
    const float* Wk_w   = (const float*)d_in[12];
    const float* Wk_b   = (const float*)d_in[13];
    const float* Wq2_w  = (const float*)d_in[14];
    const float* Wq2_b  = (const float*)d_in[15];
    const float* rel    = (const float*)d_in[16];
    const float* Wo_w   = (const float*)d_in[17];
    const float* Wo_b   = (const float*)d_in[18];
    const float* ln2_g  = (const float*)d_in[19];
    const float* ln2_b  = (const float*)d_in[20];
    const float* ff1_w  = (const float*)d_in[21];
    const float* ff1_b  = (const float*)d_in[22];
    const float* ff2_w  = (const float*)d_in[23];
    const float* ff2_b  = (const float*)d_in[24];
    // d_in[25] = indices: computed analytically on device

    float* out0  = (float*)d_out;
    float* a_out = out0 + (size_t)B_ * I_ * D_;    // [B,H,I,J]

    char* wsb = (char*)d_ws;
    const size_t MB = 1u << 20;
    // persistent bf16 transposed weights [0,28MB)
    __hip_bfloat16* WvT  = (__hip_bfloat16*)(wsb + 0 * MB);
    __hip_bfloat16* WgT  = (__hip_bfloat16*)(wsb + 2 * MB);
    __hip_bfloat16* Wq1T = (__hip_bfloat16*)(wsb + 4 * MB);
    __hip_bfloat16* WkT  = (__hip_bfloat16*)(wsb + 6 * MB);
    __hip_bfloat16* Wq2T = (__hip_bfloat16*)(wsb + 8 * MB);
    __hip_bfloat16* WoT  = (__hip_bfloat16*)(wsb + 10 * MB);
    __hip_bfloat16* ff1T = (__hip_bfloat16*)(wsb + 12 * MB);  // [4096,1024] 8MB
    __hip_bfloat16* ff2T = (__hip_bfloat16*)(wsb + 20 * MB);  // [1024,4096] 8MB
    // activations, slot-reused along the timeline (peak ~64.9MB)
    __hip_bfloat16* jbf  = (__hip_bfloat16*)(wsb + 28 * MB);  // dead after q2 proj
    __hip_bfloat16* q1b  = (__hip_bfloat16*)(wsb + 32 * MB);  // dead after aa
    __hip_bfloat16* khb  = (__hip_bfloat16*)(wsb + 36 * MB);  // dead after aa
    __hip_bfloat16* q2b  = (__hip_bfloat16*)(wsb + 40 * MB);  // dead after arf
    __hip_bfloat16* relb = (__hip_bfloat16*)(wsb + 44 * MB);  // dead after arf
    float*          arf  = (float*)        (wsb + 48 * MB);   // 16.9MB, dead after aa
    __hip_bfloat16* xnb  = (__hip_bfloat16*)(wsb + 28 * MB);  // reuse jbf
    float*          vbuf = (float*)        (wsb + 32 * MB);   // reuse q1b/khb (8MB)
    __hip_bfloat16* vt   = (__hip_bfloat16*)(wsb + 40 * MB);  // reuse q2b (4MB)
    float*          gbuf = (float*)        (wsb + 44 * MB);   // reuse relb/arf head
    __hip_bfloat16* obuf = (__hip_bfloat16*)(wsb + 52 * MB);  // 4MB
    float*          x1   = (float*)        (wsb + 56 * MB);   // 8MB
    __hip_bfloat16* x1nb = (__hip_bfloat16*)(wsb + 28 * MB);
    __hip_bfloat16* hbuf = (__hip_bfloat16*)(wsb + 32 * MB);  // 16MB

    dim3 blk(256);
    const size_t M1 = (size_t)I_ * D_;  // per-batch A stride (1M elems)

    // input converts + weight transposes
    cvt_bf16<<<2048, blk, 0, stream>>>(jin, jbf, (MROWS * D_) / 4);
    cvt_bf16<<<129, blk, 0, stream>>>(rel, relb, (R_ * D_) / 4);
    wtrans<<<dim3(16, 16), blk, 0, stream>>>(Wv_w, WvT, D_, D_);
    wtrans<<<dim3(16, 16), blk, 0, stream>>>(Wg_w, WgT, D_, D_);
    wtrans<<<dim3(16, 16), blk, 0, stream>>>(Wq1_w, Wq1T, D_, D_);
    wtrans<<<dim3(16, 16), blk, 0, stream>>>(Wk_w, WkT, D_, D_);
    wtrans<<<dim3(16, 16), blk, 0, stream>>>(Wq2_w, Wq2T, D_, D_);
    wtrans<<<dim3(16, 16), blk, 0, stream>>>(Wo_w, WoT, D_, D_);
    wtrans<<<dim3(64, 16), blk, 0, stream>>>(ff1_w, ff1T, D_, FF_);
    wtrans<<<dim3(16, 64), blk, 0, stream>>>(ff2_w, ff2T, FF_, D_);

    // q1/k/q2 projections (bf16 out)
    gemm_mfma<2, 0, 0, 1, 0><<<dim3(8, 32, 1), blk, 0, stream>>>(
        jbf, Wq1T, Wq1_b, nullptr, q1b, arf, D_, D_, D_, D_, D_, 0, 0, 0, 0, 0);
    gemm_mfma<2, 0, 0, 1, 0><<<dim3(8, 32, 1), blk, 0, stream>>>(
        jbf, WkT, Wk_b, nullptr, khb, arf, D_, D_, D_, D_, D_, 0, 0, 0, 0, 0);
    gemm_mfma<2, 0, 0, 1, 0><<<dim3(8, 32, 1), blk, 0, stream>>>(
        jbf, Wq2T, Wq2_b, nullptr, q2b, arf, D_, D_, D_, D_, D_, 0, 0, 0, 0, 0);
    // arf[bh,i,r] = q2 . rel  (batched over bh via strides)
    gemm_mfma<4, 0, 0, 0, 0><<<dim3(2, 8, 32), blk, 0, stream>>>(
        q2b, relb, nullptr, nullptr, arf, arf,
        R_, DH_, D_, D_, R_, M1, (size_t)DH_, 0, (size_t)DH_, (size_t)I_ * R_);
    // aa + gathered arf + scale -> a_out scores
    gemm_mfma<4, 0, 0, 0, 1><<<dim3(8, 8, 32), blk, 0, stream>>>(
        q1b, khb, nullptr, nullptr, a_out, arf,
        I_, DH_, D_, D_, I_, M1, (size_t)DH_, M1, (size_t)DH_, (size_t)I_ * I_);
    softmax_kernel<<<32768, blk, 0, stream>>>(a_out);

    // value/gate streams
    ln_kernel<1><<<MROWS, blk, 0, stream>>>(x, xnb, ln1_g, ln1_b);
    gemm_mfma<2, 1, 0, 0, 0><<<dim3(8, 32, 1), blk, 0, stream>>>(
        xnb, WvT, Wv_b, nullptr, vbuf, arf, D_, D_, D_, D_, D_, 0, 0, 0, 0, 0);
    ln_kernel<0><<<MROWS, blk, 0, stream>>>(vbuf, vbuf, lnv_g, lnv_b);
    vtrans<<<dim3(16, 32), blk, 0, stream>>>(vbuf, vt);
    gemm_mfma<2, 1, 0, 0, 0><<<dim3(8, 32, 1), blk, 0, stream>>>(
        xnb, WgT, Wg_b, nullptr, gbuf, arf, D_, D_, D_, D_, D_, 0, 0, 0, 0, 0);
    // PV + gate (MFMA, reg-staged fp32 a)
    pv_mfma<<<dim3(8, 1, 32), blk, 0, stream>>>(a_out, vt, gbuf, obuf);

    // output projection + residual, FF block
    gemm_mfma<2, 0, 1, 0, 0><<<dim3(8, 32, 1), blk, 0, stream>>>(
        obuf, WoT, Wo_b, x, x1, arf, D_, D_, D_, D_, D_, 0, 0, 0, 0, 0);
    ln_kernel<1><<<MROWS, blk, 0, stream>>>(x1, x1nb, ln2_g, ln2_b);
    gemm_mfma<4, 2, 0, 1, 0><<<dim3(32, 16, 1), blk, 0, stream>>>(
        x1nb, ff1T, ff1_b, nullptr, hbuf, arf, FF_, D_, D_, D_, FF_, 0, 0, 0, 0, 0);
    gemm_mfma<2, 0, 1, 0, 0><<<dim3(8, 32, 1), blk, 0, stream>>>(
        hbuf, ff2T, ff2_b, x1, out0, arf, D_, FF_, FF_, FF_, D_, 0, 0, 0, 0, 0);
}